// Round 1
// baseline (377.827 us; speedup 1.0000x reference)
//
#include <hip/hip_runtime.h>

// NSVQ reference is degenerate: each stage i slices a single row
// flattened[i:i+1] / codebooks[i:i+1], so distances has one column,
// argmin == 0 always, and quantized == codebooks[i] broadcast to all tokens.
// => out[t,:] = codebooks[0] + codebooks[1] + codebooks[2] + codebooks[3]
// for every token t. Pure write-BW-bound broadcast of a 64-float vector.
// Roofline: 256 MiB stores / ~6.3 TB/s ≈ 40 us (write-only streams may
// cap nearer ~4.5-5 TB/s => ~52-58 us).
//
// R0 note: prior session measured 378 us = ~0.69 TB/s effective — 7-9x off
// the write roofline. Baseline counters needed before changing anything:
// WRITE_SIZE should be exactly 262144 KB; if dur stays ~378 us with correct
// WRITE_SIZE, suspect the nt store path or issue limiting, and A/B plain
// stores next round.

#define N_TOKENS 1048576
#define EMB_DIM  64
#define N_FLOAT4 (N_TOKENS * (EMB_DIM / 4))   // 16,777,216 float4 stores
#define BLOCKS   4096
#define THREADS  256
#define PER_THREAD 16                          // N_FLOAT4 / (BLOCKS*THREADS)
#define BLOCK_SPAN (THREADS * PER_THREAD)      // 4096 float4 = 64 KiB per block

// Native vector type: __builtin_nontemporal_store rejects HIP_vector_type.
typedef float v4f __attribute__((ext_vector_type(4)));

__global__ __launch_bounds__(THREADS) void nsvq_broadcast_kernel(
    const float* __restrict__ codebooks, v4f* __restrict__ out4) {
  // Column group: block span (4096) and per-iter stride (256) are multiples
  // of 16, so (index & 15) == (threadIdx.x & 15) for every store this thread
  // makes — one 4-element sum covers all its stores.
  const int c = threadIdx.x & 15;

  const v4f* __restrict__ cb4 = (const v4f*)codebooks;
  v4f s0 = cb4[0 * 16 + c];
  v4f s1 = cb4[1 * 16 + c];
  v4f s2 = cb4[2 * 16 + c];
  v4f s3 = cb4[3 * 16 + c];

  // Match reference accumulation order: (((0 + cb0) + cb1) + cb2) + cb3
  v4f v = ((s0 + s1) + s2) + s3;

  // Block-contiguous: block b owns float4 indices [b*4096, (b+1)*4096).
  v4f* p = out4 + (size_t)blockIdx.x * BLOCK_SPAN + threadIdx.x;
#pragma unroll
  for (int j = 0; j < PER_THREAD; ++j) {
    // Streaming store: output is 8x L2 size and never re-read — bypass L2.
    __builtin_nontemporal_store(v, p + j * THREADS);
  }
}

extern "C" void kernel_launch(void* const* d_in, const int* in_sizes, int n_in,
                              void* d_out, int out_size, void* d_ws, size_t ws_size,
                              hipStream_t stream) {
  (void)d_ws; (void)ws_size; (void)n_in; (void)in_sizes; (void)out_size;
  const float* codebooks = (const float*)d_in[1];  // d_in[0] (input_data) unused by the math
  v4f* out4 = (v4f*)d_out;
  nsvq_broadcast_kernel<<<BLOCKS, THREADS, 0, stream>>>(codebooks, out4);
}